// Round 3
// baseline (1269.869 us; speedup 1.0000x reference)
//
#include <hip/hip_runtime.h>

// 2-layer LSTM (PyTorch gate order i,f,g,o), L=2048, B=512, INPUT=78, H=4.
//
// Kernel 1 (parallel, memory-bound): xg0[t][b][j][g] = s_g*(x[t,b,:]·W_ih0[row]+b_ih0+b_hh0),
//   row = j + 4*g, written gate-interleaved so the recurrent kernel loads one float4/lane.
//   Also writes prescaled layer-1 bias (16 floats) at ws[0..15].
// Kernel 2 (latency-bound recurrence): 8 lanes per batch element:
//   lanes [0..3]=layer0 comps 0..3, [4..7]=layer1 comps 0..3. Uniform code for both
//   layers; layer1 runs one timestep behind and receives y0 via DPP row_shr:4
//   (0x114 — lane i <- lane i-4; NOT row_shl:4/0x104, which fetches the NEXT
//   group's layer0 h and was the Round-2 absmax=0.566 bug).
//   h allgather within each quad via DPP quad_perm broadcasts. sigmoid/tanh via
//   exp2+rcp with log2(e) pre-folded into weights.
//
// ws usage: [0,64) bias1_scaled | [4096,20480) dummy-store slots | [20480, 20480+64MiB) xg0
// total required ws = 67,129,344 bytes (~64 MiB).

#define LSEQ  2048
#define BATCH 512
#define NIN   78
#define LOG2E 1.4426950408889634f

#define WS_BIAS_F  0
#define WS_DUMMY_F 1024
#define WS_XG_F    5120
#define XG_BYTES   ((unsigned)LSEQ * BATCH * 16u * 4u)

__device__ __forceinline__ float rcp_(float x) { return __builtin_amdgcn_rcpf(x); }
__device__ __forceinline__ float ex2_(float x) { return __builtin_amdgcn_exp2f(x); }

template<int CTRL>
__device__ __forceinline__ float dppf(float x) {
  int r = __builtin_amdgcn_update_dpp(0, __builtin_bit_cast(int, x), CTRL, 0xf, 0xf, false);
  return __builtin_bit_cast(float, r);
}

// ---------------- kernel 1: input projection ----------------
__global__ __launch_bounds__(256) void xg_kernel(
    const float* __restrict__ x, const float* __restrict__ Wih0,
    const float* __restrict__ bih0, const float* __restrict__ bhh0,
    const float* __restrict__ bih1, const float* __restrict__ bhh1,
    float* __restrict__ ws)
{
  const int r = blockIdx.x * 256 + threadIdx.x;
  if (r < 16) {  // prescaled layer-1 bias, layout [j*4+g]
    const int j = r >> 2, g = r & 3, row = j + 4 * g;
    const float s = (g == 2) ? 2.f * LOG2E : -LOG2E;
    ws[WS_BIAS_F + r] = s * (bih1[row] + bhh1[row]);
  }
  if (r >= LSEQ * BATCH) return;

  const float* xr = x + (size_t)r * NIN;
  float acc[16];
#pragma unroll
  for (int row = 0; row < 16; ++row) acc[row] = bih0[row] + bhh0[row];
  for (int k = 0; k < NIN; ++k) {
    const float xk = xr[k];
#pragma unroll
    for (int row = 0; row < 16; ++row) acc[row] += xk * Wih0[row * NIN + k];
  }
#pragma unroll
  for (int row = 0; row < 16; ++row) {
    const float s = ((row >> 2) == 2) ? 2.f * LOG2E : -LOG2E;
    acc[row] *= s;
  }
  float* o = ws + WS_XG_F + (size_t)r * 16;
#pragma unroll
  for (int j = 0; j < 4; ++j) {
    float4 v = make_float4(acc[j], acc[j + 4], acc[j + 8], acc[j + 12]);
    *(float4*)(o + j * 4) = v;
  }
}

// ---------------- kernel 2: recurrence ----------------
__global__ __launch_bounds__(64) void lstm_rec(
    const float* __restrict__ wsr,   // ws base (bias + xg), read-only
    float* __restrict__ wsd,        // dummy-store region base (ws + WS_DUMMY_F)
    const int* __restrict__ lens,
    const float* __restrict__ Whh0, const float* __restrict__ Whh1,
    const float* __restrict__ Wih1,
    float* __restrict__ out)
{
  const int lane  = threadIdx.x;
  const int grp   = lane >> 3;      // batch group within wave (0..7)
  const int sub   = lane & 7;
  const int layer = sub >> 2;       // 0 or 1
  const int j     = sub & 3;        // owned hidden component
  const int b     = blockIdx.x * 8 + grp;

  // per-lane prescaled weights: wa = W_hh rows {j, j+4, j+8, j+12}; wb = W_ih1 (layer1)
  float wa[4][4], wb[4][4];
  const float* whh = layer ? Whh1 : Whh0;
#pragma unroll
  for (int gi = 0; gi < 4; ++gi) {
    const int row = j + 4 * gi;
    const float s = (gi == 2) ? 2.f * LOG2E : -LOG2E;
#pragma unroll
    for (int m = 0; m < 4; ++m) {
      wa[gi][m] = s * whh[row * 4 + m];
      wb[gi][m] = layer ? s * Wih1[row * 4 + m] : 0.f;
    }
  }
  const int len = lens[b];

  // per-step float4 load: layer0 -> xg[t][b][j*4..], layer1 -> prescaled bias (stride 0)
  unsigned ofs = layer ? (unsigned)(j * 16)
                       : (unsigned)(WS_XG_F * 4 + (b * 16 + j * 4) * 4);
  const unsigned stride = layer ? 0u : (unsigned)(BATCH * 16 * 4);
  const unsigned maxofs = (unsigned)(WS_XG_F * 4) + XG_BYTES - 16u;

  // store: layer1 -> out[t][b][j]; layer0 -> private dummy slot
  float* sp = layer ? (out + b * 4 + j) : (wsd + blockIdx.x * 64 + lane);
  const int sstep = layer ? BATCH * 4 : 0;

  float h = 0.f, c = 0.f;

  auto ld4 = [&](unsigned o) -> float4 {
    o = (o > maxofs) ? maxofs : o;
    return *(const float4*)((const char*)wsr + o);
  };

  float4 buf[4];
#pragma unroll
  for (int p = 0; p < 4; ++p) { buf[p] = ld4(ofs); ofs += stride; }

  auto step = [&](const float4 b4, int t, bool do_store) {
    // allgather own-layer h within quad; ship layer0's gathered h to layer1 lanes
    // via row_shr:4 (lane i <- lane i-4). Shifted-in lanes hit wb==0 lanes only.
    float A0 = dppf<0x00>(h), A1 = dppf<0x55>(h),
          A2 = dppf<0xAA>(h), A3 = dppf<0xFF>(h);
    float B0 = dppf<0x114>(A0), B1 = dppf<0x114>(A1),
          B2 = dppf<0x114>(A2), B3 = dppf<0x114>(A3);
    float g0 = b4.x + A0 * wa[0][0] + A1 * wa[0][1] + A2 * wa[0][2] + A3 * wa[0][3]
                    + B0 * wb[0][0] + B1 * wb[0][1] + B2 * wb[0][2] + B3 * wb[0][3];
    float g1 = b4.y + A0 * wa[1][0] + A1 * wa[1][1] + A2 * wa[1][2] + A3 * wa[1][3]
                    + B0 * wb[1][0] + B1 * wb[1][1] + B2 * wb[1][2] + B3 * wb[1][3];
    float g2 = b4.z + A0 * wa[2][0] + A1 * wa[2][1] + A2 * wa[2][2] + A3 * wa[2][3]
                    + B0 * wb[2][0] + B1 * wb[2][1] + B2 * wb[2][2] + B3 * wb[2][3];
    float g3 = b4.w + A0 * wa[3][0] + A1 * wa[3][1] + A2 * wa[3][2] + A3 * wa[3][3]
                    + B0 * wb[3][0] + B1 * wb[3][1] + B2 * wb[3][2] + B3 * wb[3][3];
    // g0,g1,g3 prescaled by -log2e (sigmoid); g2 prescaled by 2*log2e (tanh)
    float si = rcp_(1.f + ex2_(g0));
    float sf = rcp_(1.f + ex2_(g1));
    float tg = 1.f - 2.f * rcp_(1.f + ex2_(g2));
    float so = rcp_(1.f + ex2_(g3));
    c = sf * c + si * tg;
    float tc = 1.f - 2.f * rcp_(1.f + ex2_(c * (2.f * LOG2E)));
    h = so * tc;
    if (do_store) {
      float val = (t < len) ? h : 0.f;
      *sp = val;
      sp += sstep;
    }
  };

  // iteration 0: layer0 computes t=0; layer1 result is garbage -> reset after
  step(buf[0], -1, false);
  if (layer) { h = 0.f; c = 0.f; }
  buf[0] = ld4(ofs); ofs += stride;

  // iteration k: layer0 computes t=k, layer1 computes (and stores) t=k-1
#pragma unroll 4
  for (int k = 1; k <= LSEQ; ++k) {
    step(buf[k & 3], k - 1, true);
    buf[k & 3] = ld4(ofs); ofs += stride;
  }
}

extern "C" void kernel_launch(void* const* d_in, const int* in_sizes, int n_in,
                              void* d_out, int out_size, void* d_ws, size_t ws_size,
                              hipStream_t stream) {
  const float* x    = (const float*)d_in[0];
  const int*   lens = (const int*)d_in[1];
  const float* Wih0 = (const float*)d_in[2];
  const float* Whh0 = (const float*)d_in[3];
  const float* bih0 = (const float*)d_in[4];
  const float* bhh0 = (const float*)d_in[5];
  const float* Wih1 = (const float*)d_in[6];
  const float* Whh1 = (const float*)d_in[7];
  const float* bih1 = (const float*)d_in[8];
  const float* bhh1 = (const float*)d_in[9];
  float* ws  = (float*)d_ws;
  float* out = (float*)d_out;

  xg_kernel<<<(LSEQ * BATCH + 255) / 256, 256, 0, stream>>>(
      x, Wih0, bih0, bhh0, bih1, bhh1, ws);
  lstm_rec<<<BATCH / 8, 64, 0, stream>>>(
      ws, ws + WS_DUMMY_F, lens, Whh0, Whh1, Wih1, out);
}

// Round 4
// 953.683 us; speedup vs baseline: 1.3315x; 1.3315x over previous
//
#include <hip/hip_runtime.h>

// 2-layer LSTM (PyTorch gate order i,f,g,o), L=2048, B=512, INPUT=78, H=4.
//
// Kernel 1 (memory-bound): LDS-staged input projection.
//   R3 post-mortem: per-thread row reads (312-B lane stride) thrashed L1/L2 ->
//   FETCH 1.57 GB (4.8x compulsory). Now each 128-thread block stages 128 rows
//   (39,936 B, float4-aligned) into LDS with coalesced float4 loads, then each
//   thread computes one row from LDS. LDS read stride 78 -> 4-way bank conflict
//   (1.58x) accepted: VALU issue dominates the compute phase.
//   Output xg0[t][b][j][g] prescaled by +-log2e, gate-interleaved for the
//   recurrent kernel's float4 loads. Bias1 (prescaled) at ws[0..15].
// Kernel 2 (latency-bound recurrence): 8 lanes per batch element:
//   lanes [0..3]=layer0 comps 0..3, [4..7]=layer1 comps 0..3. Uniform code both
//   layers; layer1 runs one timestep skewed, receives y0 via DPP row_shr:4
//   (0x114; row_shl:4 was the R2 absmax=0.566 bug). h allgather via quad_perm.
//   sigmoid/tanh = exp2+rcp with log2e folded into weights. Store predicated to
//   layer1 lanes (R4: dummy stores removed from the loop).
//
// ws: [0,64) bias1_scaled | [20480 B, 20480+64MiB) xg0. Total ~64 MiB.

#define LSEQ  2048
#define BATCH 512
#define NIN   78
#define LOG2E 1.4426950408889634f

#define WS_BIAS_F  0
#define WS_XG_F    5120
#define XG_BYTES   ((unsigned)LSEQ * BATCH * 16u * 4u)

#define RPB  128   // rows per block, kernel 1
#define TPB1 128   // threads per block, kernel 1

__device__ __forceinline__ float rcp_(float x) { return __builtin_amdgcn_rcpf(x); }
__device__ __forceinline__ float ex2_(float x) { return __builtin_amdgcn_exp2f(x); }

template<int CTRL>
__device__ __forceinline__ float dppf(float x) {
  int r = __builtin_amdgcn_update_dpp(0, __builtin_bit_cast(int, x), CTRL, 0xf, 0xf, false);
  return __builtin_bit_cast(float, r);
}

// ---------------- kernel 1: input projection (LDS-staged) ----------------
__global__ __launch_bounds__(TPB1) void xg_kernel(
    const float* __restrict__ x, const float* __restrict__ Wih0,
    const float* __restrict__ bih0, const float* __restrict__ bhh0,
    const float* __restrict__ bih1, const float* __restrict__ bhh1,
    float* __restrict__ ws)
{
  __shared__ float xs[RPB * NIN];          // 9984 floats = 39,936 B
  const int tid = threadIdx.x;
  const int r0  = blockIdx.x * RPB;

  if (blockIdx.x == 0 && tid < 16) {       // prescaled layer-1 bias [j*4+g]
    const int j = tid >> 2, g = tid & 3, row = j + 4 * g;
    const float s = (g == 2) ? 2.f * LOG2E : -LOG2E;
    ws[WS_BIAS_F + tid] = s * (bih1[row] + bhh1[row]);
  }

  // stage 128 rows, coalesced float4 (byte offset r0*312 is 16B-aligned)
  const float4* gx = (const float4*)(x + (size_t)r0 * NIN);
  float4* ls = (float4*)xs;
  for (int i = tid; i < RPB * NIN / 4; i += TPB1) ls[i] = gx[i];
  __syncthreads();

  // compute one row per thread
  const float* xr = xs + tid * NIN;
  float acc[16];
#pragma unroll
  for (int row = 0; row < 16; ++row) acc[row] = bih0[row] + bhh0[row];
  for (int k = 0; k < NIN; ++k) {
    const float xk = xr[k];
#pragma unroll
    for (int row = 0; row < 16; ++row) acc[row] += xk * Wih0[row * NIN + k];
  }
#pragma unroll
  for (int row = 0; row < 16; ++row) {
    const float s = ((row >> 2) == 2) ? 2.f * LOG2E : -LOG2E;
    acc[row] *= s;
  }
  float* o = ws + WS_XG_F + (size_t)(r0 + tid) * 16;
#pragma unroll
  for (int j = 0; j < 4; ++j) {
    float4 v = make_float4(acc[j], acc[j + 4], acc[j + 8], acc[j + 12]);
    *(float4*)(o + j * 4) = v;
  }
}

// ---------------- kernel 2: recurrence ----------------
__global__ __launch_bounds__(64) void lstm_rec(
    const float* __restrict__ wsr,   // ws base (bias + xg), read-only
    const int* __restrict__ lens,
    const float* __restrict__ Whh0, const float* __restrict__ Whh1,
    const float* __restrict__ Wih1,
    float* __restrict__ out)
{
  const int lane  = threadIdx.x;
  const int grp   = lane >> 3;      // batch group within wave (0..7)
  const int sub   = lane & 7;
  const int layer = sub >> 2;       // 0 or 1
  const int j     = sub & 3;        // owned hidden component
  const int b     = blockIdx.x * 8 + grp;

  // per-lane prescaled weights: wa = W_hh rows {j, j+4, j+8, j+12}; wb = W_ih1 (layer1)
  float wa[4][4], wb[4][4];
  const float* whh = layer ? Whh1 : Whh0;
#pragma unroll
  for (int gi = 0; gi < 4; ++gi) {
    const int row = j + 4 * gi;
    const float s = (gi == 2) ? 2.f * LOG2E : -LOG2E;
#pragma unroll
    for (int m = 0; m < 4; ++m) {
      wa[gi][m] = s * whh[row * 4 + m];
      wb[gi][m] = layer ? s * Wih1[row * 4 + m] : 0.f;
    }
  }
  const int len = lens[b];

  // per-step float4 load: layer0 -> xg[t][b][j*4..], layer1 -> prescaled bias (stride 0)
  unsigned ofs = layer ? (unsigned)(j * 16)
                       : (unsigned)(WS_XG_F * 4 + (b * 16 + j * 4) * 4);
  const unsigned stride = layer ? 0u : (unsigned)(BATCH * 16 * 4);
  const unsigned maxofs = (unsigned)(WS_XG_F * 4) + XG_BYTES - 16u;

  float* sp = out + b * 4 + j;      // only layer1 lanes actually store

  float h = 0.f, c = 0.f;

  auto ld4 = [&](unsigned o) -> float4 {
    o = (o > maxofs) ? maxofs : o;
    return *(const float4*)((const char*)wsr + o);
  };

  float4 buf[4];
#pragma unroll
  for (int p = 0; p < 4; ++p) { buf[p] = ld4(ofs); ofs += stride; }

  auto step = [&](const float4 b4, int t, bool do_store) {
    // allgather own-layer h within quad; ship layer0's gathered h to layer1
    // lanes via row_shr:4 (lane i <- lane i-4); shifted-in junk hits wb==0.
    float A0 = dppf<0x00>(h), A1 = dppf<0x55>(h),
          A2 = dppf<0xAA>(h), A3 = dppf<0xFF>(h);
    float B0 = dppf<0x114>(A0), B1 = dppf<0x114>(A1),
          B2 = dppf<0x114>(A2), B3 = dppf<0x114>(A3);
    float g0 = b4.x + A0 * wa[0][0] + A1 * wa[0][1] + A2 * wa[0][2] + A3 * wa[0][3]
                    + B0 * wb[0][0] + B1 * wb[0][1] + B2 * wb[0][2] + B3 * wb[0][3];
    float g1 = b4.y + A0 * wa[1][0] + A1 * wa[1][1] + A2 * wa[1][2] + A3 * wa[1][3]
                    + B0 * wb[1][0] + B1 * wb[1][1] + B2 * wb[1][2] + B3 * wb[1][3];
    float g2 = b4.z + A0 * wa[2][0] + A1 * wa[2][1] + A2 * wa[2][2] + A3 * wa[2][3]
                    + B0 * wb[2][0] + B1 * wb[2][1] + B2 * wb[2][2] + B3 * wb[2][3];
    float g3 = b4.w + A0 * wa[3][0] + A1 * wa[3][1] + A2 * wa[3][2] + A3 * wa[3][3]
                    + B0 * wb[3][0] + B1 * wb[3][1] + B2 * wb[3][2] + B3 * wb[3][3];
    // g0,g1,g3 prescaled by -log2e (sigmoid); g2 prescaled by 2*log2e (tanh)
    float si = rcp_(1.f + ex2_(g0));
    float sf = rcp_(1.f + ex2_(g1));
    float tg = 1.f - 2.f * rcp_(1.f + ex2_(g2));
    float so = rcp_(1.f + ex2_(g3));
    c = sf * c + si * tg;
    float tc = 1.f - 2.f * rcp_(1.f + ex2_(c * (2.f * LOG2E)));
    h = so * tc;
    if (do_store) {
      if (layer) *sp = (t < len) ? h : 0.f;   // exec-masked store, layer1 only
      sp += BATCH * 4;
    }
  };

  // iteration 0: layer0 computes t=0; layer1 result is garbage -> reset after
  step(buf[0], -1, false);
  if (layer) { h = 0.f; c = 0.f; }
  buf[0] = ld4(ofs); ofs += stride;

  // iteration k: layer0 computes t=k, layer1 computes (and stores) t=k-1
#pragma unroll 4
  for (int k = 1; k <= LSEQ; ++k) {
    step(buf[k & 3], k - 1, true);
    buf[k & 3] = ld4(ofs); ofs += stride;
  }
}

extern "C" void kernel_launch(void* const* d_in, const int* in_sizes, int n_in,
                              void* d_out, int out_size, void* d_ws, size_t ws_size,
                              hipStream_t stream) {
  const float* x    = (const float*)d_in[0];
  const int*   lens = (const int*)d_in[1];
  const float* Wih0 = (const float*)d_in[2];
  const float* Whh0 = (const float*)d_in[3];
  const float* bih0 = (const float*)d_in[4];
  const float* bhh0 = (const float*)d_in[5];
  const float* Wih1 = (const float*)d_in[6];
  const float* Whh1 = (const float*)d_in[7];
  const float* bih1 = (const float*)d_in[8];
  const float* bhh1 = (const float*)d_in[9];
  float* ws  = (float*)d_ws;
  float* out = (float*)d_out;

  xg_kernel<<<(LSEQ * BATCH) / RPB, TPB1, 0, stream>>>(
      x, Wih0, bih0, bhh0, bih1, bhh1, ws);
  lstm_rec<<<BATCH / 8, 64, 0, stream>>>(
      ws, lens, Whh0, Whh1, Wih1, out);
}

// Round 5
// 831.861 us; speedup vs baseline: 1.5265x; 1.1464x over previous
//
#include <hip/hip_runtime.h>

// 2-layer LSTM (PyTorch gate order i,f,g,o), L=2048, B=512, INPUT=78, H=4.
//
// Kernel 1 (memory-bound, ~unchanged since R4): LDS-staged input projection.
//   128-thread block stages 128 rows (39,936 B) via coalesced float4, each
//   thread computes one row. Output xg0[t][b][j][g] prescaled by +-log2e,
//   gate-interleaved for kernel 2's float4 loads. Bias1 (prescaled) at ws[0..15].
// Kernel 2 (latency-bound recurrence, R5 trim): 8 lanes per batch element:
//   lanes [0..3]=layer0 comps 0..3, [4..7]=layer1. Layer1 one step skewed,
//   receives y0 via DPP row_shr:4 (0x114; row_shl was the R2 bug). h allgather
//   via quad_perm. R5: gate sums as balanced trees in packed float2
//   (v_pk_fma_f32), prefetch depth 8, unroll 8. sigmoid/tanh = exp2+rcp with
//   log2e folded into weights (R4-verified numerics, absmax 3.9e-3).
//
// ws: [0,64) bias1_scaled | [20480 B, 20480+64MiB) xg0. Total ~64 MiB.

#define LSEQ  2048
#define BATCH 512
#define NIN   78
#define LOG2E 1.4426950408889634f

#define WS_BIAS_F  0
#define WS_XG_F    5120
#define XG_BYTES   ((unsigned)LSEQ * BATCH * 16u * 4u)

#define RPB  128
#define TPB1 128

typedef __attribute__((ext_vector_type(2))) float vf2;

__device__ __forceinline__ float rcp_(float x) { return __builtin_amdgcn_rcpf(x); }
__device__ __forceinline__ float ex2_(float x) { return __builtin_amdgcn_exp2f(x); }
__device__ __forceinline__ vf2 pkfma(vf2 a, vf2 b, vf2 c) {
  return __builtin_elementwise_fma(a, b, c);
}

template<int CTRL>
__device__ __forceinline__ float dppf(float x) {
  int r = __builtin_amdgcn_update_dpp(0, __builtin_bit_cast(int, x), CTRL, 0xf, 0xf, false);
  return __builtin_bit_cast(float, r);
}

// ---------------- kernel 1: input projection (LDS-staged) ----------------
__global__ __launch_bounds__(TPB1) void xg_kernel(
    const float* __restrict__ x, const float* __restrict__ Wih0,
    const float* __restrict__ bih0, const float* __restrict__ bhh0,
    const float* __restrict__ bih1, const float* __restrict__ bhh1,
    float* __restrict__ ws)
{
  __shared__ float xs[RPB * NIN];
  const int tid = threadIdx.x;
  const int r0  = blockIdx.x * RPB;

  if (blockIdx.x == 0 && tid < 16) {       // prescaled layer-1 bias [j*4+g]
    const int j = tid >> 2, g = tid & 3, row = j + 4 * g;
    const float s = (g == 2) ? 2.f * LOG2E : -LOG2E;
    ws[WS_BIAS_F + tid] = s * (bih1[row] + bhh1[row]);
  }

  const float4* gx = (const float4*)(x + (size_t)r0 * NIN);
  float4* ls = (float4*)xs;
  for (int i = tid; i < RPB * NIN / 4; i += TPB1) ls[i] = gx[i];
  __syncthreads();

  const float* xr = xs + tid * NIN;
  float acc[16];
#pragma unroll
  for (int row = 0; row < 16; ++row) acc[row] = bih0[row] + bhh0[row];
  for (int k = 0; k < NIN; ++k) {
    const float xk = xr[k];
#pragma unroll
    for (int row = 0; row < 16; ++row) acc[row] += xk * Wih0[row * NIN + k];
  }
#pragma unroll
  for (int row = 0; row < 16; ++row) {
    const float s = ((row >> 2) == 2) ? 2.f * LOG2E : -LOG2E;
    acc[row] *= s;
  }
  float* o = ws + WS_XG_F + (size_t)(r0 + tid) * 16;
#pragma unroll
  for (int j = 0; j < 4; ++j) {
    float4 v = make_float4(acc[j], acc[j + 4], acc[j + 8], acc[j + 12]);
    *(float4*)(o + j * 4) = v;
  }
}

// ---------------- kernel 2: recurrence ----------------
__global__ __launch_bounds__(64) void lstm_rec(
    const float* __restrict__ wsr,
    const int* __restrict__ lens,
    const float* __restrict__ Whh0, const float* __restrict__ Whh1,
    const float* __restrict__ Wih1,
    float* __restrict__ out)
{
  const int lane  = threadIdx.x;
  const int grp   = lane >> 3;
  const int sub   = lane & 7;
  const int layer = sub >> 2;
  const int j     = sub & 3;
  const int b     = blockIdx.x * 8 + grp;

  // packed prescaled weights: pair01 = gates(i,f), pair23 = gates(g,o)
  // wA01[m] = { s_i*Whh[(j+0)*4+m], s_f*Whh[(j+4)*4+m] } etc.
  vf2 wA01[4], wA23[4], wB01[4], wB23[4];
  const float* whh = layer ? Whh1 : Whh0;
#pragma unroll
  for (int m = 0; m < 4; ++m) {
    const float s0 = -LOG2E, s1 = -LOG2E, s2 = 2.f * LOG2E, s3 = -LOG2E;
    wA01[m] = vf2{ s0 * whh[(j + 0) * 4 + m],  s1 * whh[(j + 4) * 4 + m] };
    wA23[m] = vf2{ s2 * whh[(j + 8) * 4 + m],  s3 * whh[(j + 12) * 4 + m] };
    const float t0 = layer ? s0 * Wih1[(j + 0) * 4 + m]  : 0.f;
    const float t1 = layer ? s1 * Wih1[(j + 4) * 4 + m]  : 0.f;
    const float t2 = layer ? s2 * Wih1[(j + 8) * 4 + m]  : 0.f;
    const float t3 = layer ? s3 * Wih1[(j + 12) * 4 + m] : 0.f;
    wB01[m] = vf2{ t0, t1 };
    wB23[m] = vf2{ t2, t3 };
  }
  const int len = lens[b];

  unsigned ofs = layer ? (unsigned)(j * 16)
                       : (unsigned)(WS_XG_F * 4 + (b * 16 + j * 4) * 4);
  const unsigned stride = layer ? 0u : (unsigned)(BATCH * 16 * 4);
  const unsigned maxofs = (unsigned)(WS_XG_F * 4) + XG_BYTES - 16u;

  float* sp = out + b * 4 + j;      // only layer1 lanes actually store

  float h = 0.f, c = 0.f;

  auto ld4 = [&](unsigned o) -> float4 {
    o = (o > maxofs) ? maxofs : o;
    return *(const float4*)((const char*)wsr + o);
  };

  float4 buf[8];
#pragma unroll
  for (int p = 0; p < 8; ++p) { buf[p] = ld4(ofs); ofs += stride; }

  auto step = [&](const float4 b4, int t, bool do_store) {
    // allgather own-layer h within quad; ship layer0's gathered h to layer1
    // lanes via row_shr:4 (lane i <- lane i-4); shifted-in junk hits wB==0.
    float A0 = dppf<0x00>(h), A1 = dppf<0x55>(h),
          A2 = dppf<0xAA>(h), A3 = dppf<0xFF>(h);
    float B0 = dppf<0x114>(A0), B1 = dppf<0x114>(A1),
          B2 = dppf<0x114>(A2), B3 = dppf<0x114>(A3);
    vf2 Av0 = { A0, A0 }, Av1 = { A1, A1 }, Av2 = { A2, A2 }, Av3 = { A3, A3 };
    vf2 Bv0 = { B0, B0 }, Bv1 = { B1, B1 }, Bv2 = { B2, B2 }, Bv3 = { B3, B3 };

    // balanced trees: two depth-4 fma chains + 1 add per gate pair
    vf2 p01 = pkfma(Av0, wA01[0], vf2{ b4.x, b4.y });
    p01 = pkfma(Av1, wA01[1], p01);
    p01 = pkfma(Bv0, wB01[0], p01);
    p01 = pkfma(Bv1, wB01[1], p01);
    vf2 q01 = Av2 * wA01[2];
    q01 = pkfma(Av3, wA01[3], q01);
    q01 = pkfma(Bv2, wB01[2], q01);
    q01 = pkfma(Bv3, wB01[3], q01);
    vf2 g01 = p01 + q01;

    vf2 p23 = pkfma(Av0, wA23[0], vf2{ b4.z, b4.w });
    p23 = pkfma(Av1, wA23[1], p23);
    p23 = pkfma(Bv0, wB23[0], p23);
    p23 = pkfma(Bv1, wB23[1], p23);
    vf2 q23 = Av2 * wA23[2];
    q23 = pkfma(Av3, wA23[3], q23);
    q23 = pkfma(Bv2, wB23[2], q23);
    q23 = pkfma(Bv3, wB23[3], q23);
    vf2 g23 = p23 + q23;

    // g01.x,g01.y,g23.y prescaled by -log2e (sigmoid); g23.x by 2*log2e (tanh)
    float si = rcp_(1.f + ex2_(g01.x));
    float sf = rcp_(1.f + ex2_(g01.y));
    float tg = fmaf(-2.f, rcp_(1.f + ex2_(g23.x)), 1.f);
    float so = rcp_(1.f + ex2_(g23.y));
    c = fmaf(sf, c, si * tg);
    float tc = fmaf(-2.f, rcp_(1.f + ex2_(c * (2.f * LOG2E))), 1.f);
    h = so * tc;
    if (do_store) {
      if (layer) *sp = (t < len) ? h : 0.f;   // exec-masked store, layer1 only
      sp += BATCH * 4;
    }
  };

  // iteration 0: layer0 computes t=0; layer1 result is garbage -> reset after
  step(buf[0], -1, false);
  if (layer) { h = 0.f; c = 0.f; }
  buf[0] = ld4(ofs); ofs += stride;

  // iteration k: layer0 computes t=k, layer1 computes (and stores) t=k-1
#pragma unroll 8
  for (int k = 1; k <= LSEQ; ++k) {
    step(buf[k & 7], k - 1, true);
    buf[k & 7] = ld4(ofs); ofs += stride;
  }
}

extern "C" void kernel_launch(void* const* d_in, const int* in_sizes, int n_in,
                              void* d_out, int out_size, void* d_ws, size_t ws_size,
                              hipStream_t stream) {
  const float* x    = (const float*)d_in[0];
  const int*   lens = (const int*)d_in[1];
  const float* Wih0 = (const float*)d_in[2];
  const float* Whh0 = (const float*)d_in[3];
  const float* bih0 = (const float*)d_in[4];
  const float* bhh0 = (const float*)d_in[5];
  const float* Wih1 = (const float*)d_in[6];
  const float* Whh1 = (const float*)d_in[7];
  const float* bih1 = (const float*)d_in[8];
  const float* bhh1 = (const float*)d_in[9];
  float* ws  = (float*)d_ws;
  float* out = (float*)d_out;

  xg_kernel<<<(LSEQ * BATCH) / RPB, TPB1, 0, stream>>>(
      x, Wih0, bih0, bhh0, bih1, bhh1, ws);
  lstm_rec<<<BATCH / 8, 64, 0, stream>>>(
      ws, lens, Whh0, Whh1, Wih1, out);
}